// Round 3
// baseline (274.542 us; speedup 1.0000x reference)
//
#include <hip/hip_runtime.h>

// Mobius addition broadcast: out[m,n,:] =
//   ((1 + 2*xy + nx)*B[n] + (1 - nB)*x[m]) / (1 + 2*xy + nB*nx)
// M=2048, N=1024, D=128, fp32. Output 1.07 GB -> write-BW bound.
//
// R3: fused kernel (two-phase was net-negative in R2), PLAIN stores.
// Single variable vs R1: __builtin_nontemporal_store -> regular store.
// fillBufferAligned sustains 6.5 TB/s with plain stores; NT bypasses L2
// and is the prime suspect for R1's 4.4 TB/s cap.

#define M_DIM 2048
#define N_DIM 1024
#define D_DIM 128
#define NPAIRS ((long long)M_DIM * N_DIM)

using f4 = __attribute__((ext_vector_type(4))) float;

__device__ __forceinline__ float dot4(f4 u, f4 v) {
    return u.x * v.x + u.y * v.y + u.z * v.z + u.w * v.w;
}

__global__ __launch_bounds__(256) void mobius_fused_kernel(
    const float* __restrict__ B, const float* __restrict__ x,
    float* __restrict__ out)
{
    const int lane = threadIdx.x & 31;                 // lane within half-wave
    const long long hw  = ((long long)blockIdx.x * blockDim.x + threadIdx.x) >> 5;
    const long long nhw = ((long long)gridDim.x * blockDim.x) >> 5;

    for (long long p = hw; p < NPAIRS; p += nhw) {
        const int m = (int)(p >> 10);      // N = 1024 = 2^10
        const int n = (int)(p & (N_DIM - 1));

        const f4 xv = *reinterpret_cast<const f4*>(x + (long long)m * D_DIM + lane * 4);
        const f4 bv = *reinterpret_cast<const f4*>(B + (long long)n * D_DIM + lane * 4);

        float xy  = dot4(xv, bv);
        float sxx = dot4(xv, xv);
        float sbb = dot4(bv, bv);

        // Reduce across the 32-lane half-wave (masks 1..16 stay within the
        // 32-lane half of the 64-lane wave).
        #pragma unroll
        for (int off = 1; off < 32; off <<= 1) {
            xy  += __shfl_xor(xy,  off, 64);
            sxx += __shfl_xor(sxx, off, 64);
            sbb += __shfl_xor(sbb, off, 64);
        }

        const float coefB = 1.0f + 2.0f * xy + sxx;   // 1 + 2<x,B> + |x|^2
        const float coefx = 1.0f - sbb;               // 1 - |B|^2
        const float r     = 1.0f / (1.0f + 2.0f * xy + sbb * sxx);

        f4 o;
        o.x = (coefB * bv.x + coefx * xv.x) * r;
        o.y = (coefB * bv.y + coefx * xv.y) * r;
        o.z = (coefB * bv.z + coefx * xv.z) * r;
        o.w = (coefB * bv.w + coefx * xv.w) * r;

        // PLAIN store (the single change vs R1's nontemporal store).
        *reinterpret_cast<f4*>(out + p * D_DIM + lane * 4) = o;
    }
}

extern "C" void kernel_launch(void* const* d_in, const int* in_sizes, int n_in,
                              void* d_out, int out_size, void* d_ws, size_t ws_size,
                              hipStream_t stream) {
    const float* B = (const float*)d_in[0];   // [N, D]
    const float* x = (const float*)d_in[1];   // [M, D]
    float* out = (float*)d_out;               // [M, N, D]

    const int block = 256;
    const int grid  = 2048;  // 8 blocks/CU on 256 CUs -> 32 waves/CU

    mobius_fused_kernel<<<grid, block, 0, stream>>>(B, x, out);
}

// Round 4
// 173.605 us; speedup vs baseline: 1.5814x; 1.5814x over previous
//
#include <hip/hip_runtime.h>

// Mobius addition broadcast: out[m,n,:] =
//   ((1 + 2*xy + nx)*B[n] + (1 - nB)*x[m]) / (1 + 2*xy + nB*nx)
// M=2048, N=1024, D=128, fp32. Output 1.07 GB -> write-BW bound.
//
// R4: FLAT GRID, no grid-stride loop. Each block = 32 consecutive pairs
// (16 KB contiguous output), then exits. Removes the per-iteration
// load-after-store vmcnt serialization (vmcnt retires in order: waiting on
// next iteration's loads transitively waited on the previous store's full
// HBM retirement) and mimics fillBuffer's linearly-sweeping write frontier
// (6.5 TB/s at 11% occupancy). NT stores kept (R1 245 us NT > R3 274 us plain).

#define M_DIM 2048
#define N_DIM 1024
#define D_DIM 128
#define NPAIRS ((long long)M_DIM * N_DIM)
#define PAIRS_PER_BLOCK 32
#define PAIRS_PER_HALF 4

using f4 = __attribute__((ext_vector_type(4))) float;

__device__ __forceinline__ float dot4(f4 u, f4 v) {
    return u.x * v.x + u.y * v.y + u.z * v.z + u.w * v.w;
}

__device__ __forceinline__ float hreduce(float v) {
    // Sum across the 32-lane half-wave (masks 1..16 stay within each half
    // of the 64-lane wave).
    #pragma unroll
    for (int off = 1; off < 32; off <<= 1) v += __shfl_xor(v, off, 64);
    return v;
}

__global__ __launch_bounds__(256) void mobius_flat_kernel(
    const float* __restrict__ B, const float* __restrict__ x,
    float* __restrict__ out)
{
    const int lane = threadIdx.x & 31;            // lane within half-wave
    const int half = threadIdx.x >> 5;            // 0..7

    // Block b owns pairs [b*32, b*32+32); half-wave owns 4 consecutive pairs.
    const long long p0 = (long long)blockIdx.x * PAIRS_PER_BLOCK
                       + (long long)half * PAIRS_PER_HALF;
    const int m  = (int)(p0 >> 10);               // constant within block
    const int n0 = (int)(p0 & (N_DIM - 1));

    // ---- hoisted loads: one x row (shared) + 4 B rows ----
    const f4 xv = *reinterpret_cast<const f4*>(
        x + (long long)m * D_DIM + lane * 4);
    f4 bv[PAIRS_PER_HALF];
    #pragma unroll
    for (int j = 0; j < PAIRS_PER_HALF; ++j)
        bv[j] = *reinterpret_cast<const f4*>(
            B + (long long)(n0 + j) * D_DIM + lane * 4);

    // ---- reductions: sxx once, xy/sbb per pair ----
    const float sxx = hreduce(dot4(xv, xv));
    float xy[PAIRS_PER_HALF], sbb[PAIRS_PER_HALF];
    #pragma unroll
    for (int j = 0; j < PAIRS_PER_HALF; ++j) {
        xy[j]  = hreduce(dot4(xv, bv[j]));
        sbb[j] = hreduce(dot4(bv[j], bv[j]));
    }

    // ---- compute + 4 NT stores (2 KB contiguous per half-wave) ----
    #pragma unroll
    for (int j = 0; j < PAIRS_PER_HALF; ++j) {
        const float coefB = 1.0f + 2.0f * xy[j] + sxx;
        const float coefx = 1.0f - sbb[j];
        const float r     = 1.0f / (1.0f + 2.0f * xy[j] + sbb[j] * sxx);
        f4 o;
        o.x = (coefB * bv[j].x + coefx * xv.x) * r;
        o.y = (coefB * bv[j].y + coefx * xv.y) * r;
        o.z = (coefB * bv[j].z + coefx * xv.z) * r;
        o.w = (coefB * bv[j].w + coefx * xv.w) * r;
        __builtin_nontemporal_store(o,
            reinterpret_cast<f4*>(out + (p0 + j) * D_DIM + lane * 4));
    }
}

extern "C" void kernel_launch(void* const* d_in, const int* in_sizes, int n_in,
                              void* d_out, int out_size, void* d_ws, size_t ws_size,
                              hipStream_t stream) {
    const float* B = (const float*)d_in[0];   // [N, D]
    const float* x = (const float*)d_in[1];   // [M, D]
    float* out = (float*)d_out;               // [M, N, D]

    const int grid = (int)(NPAIRS / PAIRS_PER_BLOCK);   // 65536 blocks
    mobius_flat_kernel<<<grid, 256, 0, stream>>>(B, x, out);
}